// Round 5
// baseline (651.626 us; speedup 1.0000x reference)
//
#include <hip/hip_runtime.h>

// MaxPool2d 2x2 stride 2 on (32, 64, 224, 224) fp32 -> (32, 64, 112, 112).
// SAME padding is zero (224 even), so each output = max over a disjoint 2x2.
//
// R3 = CALIBRATION ROUND: the bench dur_us (549.5 R1, 553.4 R2) is dominated
// by ~395 us of fixed harness work in the timed region (d_in restore copy +
// 1.64 GB 0xAA poison fills, visible in rocprof as fillBufferAligned @ 252us).
// The kernel itself is <252 us (absent from top-5) but its exact time is
// unknown. Launching the IDENTICAL kernel twice (idempotent: same inputs,
// same outputs) makes  t_kernel ~= dur_us - 553,  resolving "at floor (~85us)"
// vs "2x off floor (~160us)" before deciding whether to keep optimizing.
//
// Traffic per pass: 411 MB read + 103 MB write => ~82 us floor at 6.3 TB/s.

#define TOTAL_ITEMS (32 * 64 * 112 * 56)  // 12,845,056 float4-input chunks

__global__ __launch_bounds__(256) void maxpool_2x2_kernel(
    const float* __restrict__ in, float* __restrict__ out) {
    const int total = TOTAL_ITEMS;
    const int stride = gridDim.x * blockDim.x;
    for (int idx = blockIdx.x * blockDim.x + threadIdx.x; idx < total; idx += stride) {
        const int r = idx / 56;  // row-pair index (global, plane-agnostic)
        const float* src = in + (size_t)4 * idx + (size_t)224 * r;

        const float4 a = *reinterpret_cast<const float4*>(src);        // row 2r
        const float4 b = *reinterpret_cast<const float4*>(src + 224);  // row 2r+1

        float2 o;
        o.x = fmaxf(fmaxf(a.x, a.y), fmaxf(b.x, b.y));
        o.y = fmaxf(fmaxf(a.z, a.w), fmaxf(b.z, b.w));

        *reinterpret_cast<float2*>(out + (size_t)2 * idx) = o;
    }
}

extern "C" void kernel_launch(void* const* d_in, const int* in_sizes, int n_in,
                              void* d_out, int out_size, void* d_ws, size_t ws_size,
                              hipStream_t stream) {
    const float* X = (const float*)d_in[0];
    float* out = (float*)d_out;
    // CALIBRATION: two identical, idempotent launches. dur_us - 553 ~= t_kernel.
    maxpool_2x2_kernel<<<2048, 256, 0, stream>>>(X, out);
    maxpool_2x2_kernel<<<2048, 256, 0, stream>>>(X, out);
}

// Round 6
// 555.057 us; speedup vs baseline: 1.1740x; 1.1740x over previous
//
#include <hip/hip_runtime.h>

// MaxPool2d 2x2 stride 2 on (32, 64, 224, 224) fp32 -> (32, 64, 112, 112).
// SAME padding is zero (224 even), so each output = max over a disjoint 2x2.
//
// FINAL (revert of R3/R5 calibration double-launch to single launch).
//
// Calibration result (R2 vs R5): t_kernel ~= 651.6 - 553.4 = 98 us for
// 514 MB of compulsory HBM traffic (411 MB read + 103 MB write) =
// 5.25 TB/s effective = 83% of the 6.3 TB/s achievable ceiling. The bench
// dur_us (~553) additionally contains ~455 us of fixed harness restore/
// poison work (rocprof: fillBufferAligned 1.64 GB @ ~6.5 TB/s each timed
// iteration). Access-pattern insensitivity (R1 == R2 within noise) confirms
// the kernel is HBM-bound, not coalescing- or VALU-bound.
//
// Work item idx = r*56 + c over 458752 row-pairs x 56 float4-chunks:
//   loads  float4 at in + 4*idx + 224*r      (row 2r,   16 B/lane, coalesced)
//          float4 at same + 224              (row 2r+1, 16 B/lane, coalesced)
//   stores float2 at out + 2*idx             (8 B/lane, coalesced)

#define TOTAL_ITEMS (32 * 64 * 112 * 56)  // 12,845,056 float4-input chunks

__global__ __launch_bounds__(256) void maxpool_2x2_kernel(
    const float* __restrict__ in, float* __restrict__ out) {
    const int total = TOTAL_ITEMS;
    const int stride = gridDim.x * blockDim.x;
    for (int idx = blockIdx.x * blockDim.x + threadIdx.x; idx < total; idx += stride) {
        const int r = idx / 56;  // row-pair index (global, plane-agnostic)
        const float* src = in + (size_t)4 * idx + (size_t)224 * r;

        const float4 a = *reinterpret_cast<const float4*>(src);        // row 2r
        const float4 b = *reinterpret_cast<const float4*>(src + 224);  // row 2r+1

        float2 o;
        o.x = fmaxf(fmaxf(a.x, a.y), fmaxf(b.x, b.y));
        o.y = fmaxf(fmaxf(a.z, a.w), fmaxf(b.z, b.w));

        *reinterpret_cast<float2*>(out + (size_t)2 * idx) = o;
    }
}

extern "C" void kernel_launch(void* const* d_in, const int* in_sizes, int n_in,
                              void* d_out, int out_size, void* d_ws, size_t ws_size,
                              hipStream_t stream) {
    const float* X = (const float*)d_in[0];
    float* out = (float*)d_out;
    // 2048 blocks x 256 threads = 8 blocks/CU; ~24 grid-stride iterations each.
    maxpool_2x2_kernel<<<2048, 256, 0, stream>>>(X, out);
}